// Round 1
// baseline (1997.593 us; speedup 1.0000x reference)
//
#include <hip/hip_runtime.h>
#include <math.h>

// Problem constants
constexpr int BB  = 16;
constexpr int CH  = 96;            // CIN == COUT == 96
constexpr int HH  = 96;
constexpr int WW  = 96;
constexpr int HWI = HH * WW;       // 9216
constexpr int CHW = CH * HWI;      // 884736
constexpr int IMG = BB * CHW;      // 14155776 floats per [B,C,H,W] tensor
constexpr int ATT = BB * CH * CH * 9;  // 1327104 floats

// ---------------------------------------------------------------------------
// Kernel 1: dual 3x3 conv (Y1 = conv(x,W1), Y2 = conv(x,W2)), fp32 direct.
// Block: 256 threads -> one (b, 8-channel co group, 32x32 spatial tile).
// Each thread: 4 adjacent output cols x 1 row x 8 co x 2 convs = 64 accs.
// Weights are block-uniform -> compiler scalarizes to s_load (frees VALU).
// ---------------------------------------------------------------------------
__global__ __launch_bounds__(256) void conv_dual(
    const float* __restrict__ x,
    const float* __restrict__ W1, const float* __restrict__ W2,
    float* __restrict__ Y1, float* __restrict__ Y2)
{
  const int b   = blockIdx.z;
  const int co0 = blockIdx.x * 8;
  const int ty0 = (blockIdx.y / 3) * 32;
  const int tx0 = (blockIdx.y % 3) * 32;
  const int tid = threadIdx.x;
  const int txg = tid & 7;     // 0..7 -> output cols 4*txg .. 4*txg+3
  const int ty  = tid >> 3;    // 0..31 -> output row

  __shared__ float xs[34][36]; // 32+2 halo rows, cols padded 34->36 (16B align)

  float acc[2][8][4];
#pragma unroll
  for (int s = 0; s < 2; ++s)
#pragma unroll
    for (int c = 0; c < 8; ++c)
#pragma unroll
      for (int p = 0; p < 4; ++p) acc[s][c][p] = 0.f;

  const float* xb = x + b * CHW;

  for (int ci = 0; ci < CH; ++ci) {
    __syncthreads();
    for (int idx = tid; idx < 34 * 34; idx += 256) {
      const int i  = idx / 34;
      const int j  = idx - i * 34;
      const int gy = ty0 - 1 + i;
      const int gx = tx0 - 1 + j;
      float v = 0.f;
      if ((unsigned)gy < 96u && (unsigned)gx < 96u)
        v = xb[ci * HWI + gy * WW + gx];
      xs[i][j] = v;
    }
    __syncthreads();

    float xv[3][6];
#pragma unroll
    for (int i = 0; i < 3; ++i)
#pragma unroll
      for (int j = 0; j < 6; ++j) xv[i][j] = xs[ty + i][txg * 4 + j];

#pragma unroll
    for (int c = 0; c < 8; ++c) {
      const int wbase = (co0 + c) * (CH * 9) + ci * 9;
      {
        float w[9];
#pragma unroll
        for (int k = 0; k < 9; ++k) w[k] = W1[wbase + k];
#pragma unroll
        for (int p = 0; p < 4; ++p) {
          float s0 = acc[0][c][p];
#pragma unroll
          for (int i = 0; i < 3; ++i)
#pragma unroll
            for (int j = 0; j < 3; ++j)
              s0 = fmaf(w[i * 3 + j], xv[i][p + j], s0);
          acc[0][c][p] = s0;
        }
      }
      {
        float w[9];
#pragma unroll
        for (int k = 0; k < 9; ++k) w[k] = W2[wbase + k];
#pragma unroll
        for (int p = 0; p < 4; ++p) {
          float s0 = acc[1][c][p];
#pragma unroll
          for (int i = 0; i < 3; ++i)
#pragma unroll
            for (int j = 0; j < 3; ++j)
              s0 = fmaf(w[i * 3 + j], xv[i][p + j], s0);
          acc[1][c][p] = s0;
        }
      }
    }
  }

  const int oy = ty0 + ty, ox = tx0 + txg * 4;
#pragma unroll
  for (int c = 0; c < 8; ++c) {
    const size_t off = (size_t)b * CHW + (size_t)(co0 + c) * HWI + oy * WW + ox;
    *(float4*)(Y1 + off) = make_float4(acc[0][c][0], acc[0][c][1], acc[0][c][2], acc[0][c][3]);
    *(float4*)(Y2 + off) = make_float4(acc[1][c][0], acc[1][c][1], acc[1][c][2], acc[1][c][3]);
  }
}

// ---------------------------------------------------------------------------
// Kernel 1b: single 3x3 conv (Y3 = conv(x,W3)).
// ---------------------------------------------------------------------------
__global__ __launch_bounds__(256) void conv_single(
    const float* __restrict__ x, const float* __restrict__ W3,
    float* __restrict__ Y3)
{
  const int b   = blockIdx.z;
  const int co0 = blockIdx.x * 8;
  const int ty0 = (blockIdx.y / 3) * 32;
  const int tx0 = (blockIdx.y % 3) * 32;
  const int tid = threadIdx.x;
  const int txg = tid & 7;
  const int ty  = tid >> 3;

  __shared__ float xs[34][36];

  float acc[8][4];
#pragma unroll
  for (int c = 0; c < 8; ++c)
#pragma unroll
    for (int p = 0; p < 4; ++p) acc[c][p] = 0.f;

  const float* xb = x + b * CHW;

  for (int ci = 0; ci < CH; ++ci) {
    __syncthreads();
    for (int idx = tid; idx < 34 * 34; idx += 256) {
      const int i  = idx / 34;
      const int j  = idx - i * 34;
      const int gy = ty0 - 1 + i;
      const int gx = tx0 - 1 + j;
      float v = 0.f;
      if ((unsigned)gy < 96u && (unsigned)gx < 96u)
        v = xb[ci * HWI + gy * WW + gx];
      xs[i][j] = v;
    }
    __syncthreads();

    float xv[3][6];
#pragma unroll
    for (int i = 0; i < 3; ++i)
#pragma unroll
      for (int j = 0; j < 6; ++j) xv[i][j] = xs[ty + i][txg * 4 + j];

#pragma unroll
    for (int c = 0; c < 8; ++c) {
      const int wbase = (co0 + c) * (CH * 9) + ci * 9;
      float w[9];
#pragma unroll
      for (int k = 0; k < 9; ++k) w[k] = W3[wbase + k];
#pragma unroll
      for (int p = 0; p < 4; ++p) {
        float s0 = acc[c][p];
#pragma unroll
        for (int i = 0; i < 3; ++i)
#pragma unroll
          for (int j = 0; j < 3; ++j)
            s0 = fmaf(w[i * 3 + j], xv[i][p + j], s0);
        acc[c][p] = s0;
      }
    }
  }

  const int oy = ty0 + ty, ox = tx0 + txg * 4;
#pragma unroll
  for (int c = 0; c < 8; ++c) {
    const size_t off = (size_t)b * CHW + (size_t)(co0 + c) * HWI + oy * WW + ox;
    *(float4*)(Y3 + off) = make_float4(acc[c][0], acc[c][1], acc[c][2], acc[c][3]);
  }
}

// ---------------------------------------------------------------------------
// Kernel 2: attention Gram GEMM.
// attn[b,k,c,d] = sum over the 32x32 pixel subset {h%3==kh, w%3==kw} of
//                 Y1[b,c,p] * Y2[b,d,p].
// One 1024-thread block per (b,k) = 144 blocks; thread (tc,td) computes a
// 3x3 sub-tile of the 96x96 output, K staged through LDS 32 at a time.
// Output written directly in transposed layout attnT[b][d][c][k] so the
// softmax reads/writes are contiguous.
// ---------------------------------------------------------------------------
__global__ __launch_bounds__(1024) void attn_gemm(
    const float* __restrict__ Y1, const float* __restrict__ Y2,
    float* __restrict__ attnT)
{
  const int b  = blockIdx.x / 9;
  const int k  = blockIdx.x % 9;
  const int kh = k / 3, kw = k % 3;
  const int tid = threadIdx.x;
  const int td = tid & 31;
  const int tc = tid >> 5;

  __shared__ float as[96][33];  // +1 pad: conflict-free bs reads
  __shared__ float bs[96][33];

  float acc[3][3];
#pragma unroll
  for (int r = 0; r < 3; ++r)
#pragma unroll
    for (int s = 0; s < 3; ++s) acc[r][s] = 0.f;

  const float* y1b = Y1 + (size_t)b * CHW;
  const float* y2b = Y2 + (size_t)b * CHW;

  for (int i = 0; i < 32; ++i) {        // block-row i of the pixel grid
    __syncthreads();
    const int row = (3 * i + kh) * WW + kw;
    for (int t = tid; t < 96 * 32; t += 1024) {
      const int c = t >> 5;
      const int j = t & 31;
      as[c][j] = y1b[c * HWI + row + 3 * j];
      bs[c][j] = y2b[c * HWI + row + 3 * j];
    }
    __syncthreads();

#pragma unroll 4
    for (int j = 0; j < 32; ++j) {
      const float a0 = as[tc][j], a1 = as[tc + 32][j], a2 = as[tc + 64][j];
      const float b0 = bs[td][j], b1 = bs[td + 32][j], b2 = bs[td + 64][j];
      acc[0][0] = fmaf(a0, b0, acc[0][0]);
      acc[0][1] = fmaf(a0, b1, acc[0][1]);
      acc[0][2] = fmaf(a0, b2, acc[0][2]);
      acc[1][0] = fmaf(a1, b0, acc[1][0]);
      acc[1][1] = fmaf(a1, b1, acc[1][1]);
      acc[1][2] = fmaf(a1, b2, acc[1][2]);
      acc[2][0] = fmaf(a2, b0, acc[2][0]);
      acc[2][1] = fmaf(a2, b1, acc[2][1]);
      acc[2][2] = fmaf(a2, b2, acc[2][2]);
    }
  }

#pragma unroll
  for (int r = 0; r < 3; ++r)
#pragma unroll
    for (int s = 0; s < 3; ++s) {
      const int c = tc + 32 * r;
      const int d = td + 32 * s;
      attnT[((size_t)(b * CH + d) * CH + c) * 9 + k] = acc[r][s];
    }
}

// ---------------------------------------------------------------------------
// Kernel 3: softmax over m = c*9+k (864 values) for each (b,d) row.
// Contiguous reads/writes thanks to attnT layout. Scale 1/sqrt(864).
// ---------------------------------------------------------------------------
__global__ __launch_bounds__(256) void softmax_k(
    const float* __restrict__ attnT, float* __restrict__ attnW)
{
  const int bd = blockIdx.x;               // 0 .. 16*96-1
  const float* src = attnT + (size_t)bd * 864;
  float* dst = attnW + (size_t)bd * 864;
  const float rs = 0.0340216824f;          // 1/sqrt(864)
  const int tid = threadIdx.x;

  float v0 = src[tid];
  float v1 = src[tid + 256];
  float v2 = src[tid + 512];
  float v3 = (tid < 96) ? src[tid + 768] : -3.0e38f;

  float mx = fmaxf(fmaxf(v0, v1), fmaxf(v2, v3));

  __shared__ float red[256];
  red[tid] = mx;
  __syncthreads();
#pragma unroll
  for (int s = 128; s > 0; s >>= 1) {
    if (tid < s) red[tid] = fmaxf(red[tid], red[tid + s]);
    __syncthreads();
  }
  mx = red[0];
  __syncthreads();

  const float e0 = expf((v0 - mx) * rs);
  const float e1 = expf((v1 - mx) * rs);
  const float e2 = expf((v2 - mx) * rs);
  const float e3 = (tid < 96) ? expf((v3 - mx) * rs) : 0.f;

  red[tid] = e0 + e1 + e2 + e3;
  __syncthreads();
#pragma unroll
  for (int s = 128; s > 0; s >>= 1) {
    if (tid < s) red[tid] += red[tid + s];
    __syncthreads();
  }
  const float inv = 1.f / red[0];

  dst[tid]       = e0 * inv;
  dst[tid + 256] = e1 * inv;
  dst[tid + 512] = e2 * inv;
  if (tid < 96) dst[tid + 768] = e3 * inv;
}

// ---------------------------------------------------------------------------
// Kernel 4: attention-weighted 3x3 conv:
// out[b,d,h,w] = sum_{c,kh,kw} attnW[b,d,c,kh,kw] * Y3pad[b,c,h+kh-1,w+kw-1]
// Same structure as conv_single; weights indexed per (b, d-group) -> still
// block-uniform -> scalar loads.
// ---------------------------------------------------------------------------
__global__ __launch_bounds__(256) void conv_attn(
    const float* __restrict__ Y3, const float* __restrict__ AW,
    float* __restrict__ out)
{
  const int b   = blockIdx.z;
  const int d0  = blockIdx.x * 8;
  const int ty0 = (blockIdx.y / 3) * 32;
  const int tx0 = (blockIdx.y % 3) * 32;
  const int tid = threadIdx.x;
  const int txg = tid & 7;
  const int ty  = tid >> 3;

  __shared__ float xs[34][36];

  float acc[8][4];
#pragma unroll
  for (int c = 0; c < 8; ++c)
#pragma unroll
    for (int p = 0; p < 4; ++p) acc[c][p] = 0.f;

  const float* yb = Y3 + (size_t)b * CHW;

  for (int ci = 0; ci < CH; ++ci) {
    __syncthreads();
    for (int idx = tid; idx < 34 * 34; idx += 256) {
      const int i  = idx / 34;
      const int j  = idx - i * 34;
      const int gy = ty0 - 1 + i;
      const int gx = tx0 - 1 + j;
      float v = 0.f;
      if ((unsigned)gy < 96u && (unsigned)gx < 96u)
        v = yb[ci * HWI + gy * WW + gx];
      xs[i][j] = v;
    }
    __syncthreads();

    float xv[3][6];
#pragma unroll
    for (int i = 0; i < 3; ++i)
#pragma unroll
      for (int j = 0; j < 6; ++j) xv[i][j] = xs[ty + i][txg * 4 + j];

#pragma unroll
    for (int c = 0; c < 8; ++c) {
      const float* wp = AW + ((size_t)(b * CH) + d0 + c) * 864 + ci * 9;
      float w[9];
#pragma unroll
      for (int k = 0; k < 9; ++k) w[k] = wp[k];
#pragma unroll
      for (int p = 0; p < 4; ++p) {
        float s0 = acc[c][p];
#pragma unroll
        for (int i = 0; i < 3; ++i)
#pragma unroll
          for (int j = 0; j < 3; ++j)
            s0 = fmaf(w[i * 3 + j], xv[i][p + j], s0);
        acc[c][p] = s0;
      }
    }
  }

  const int oy = ty0 + ty, ox = tx0 + txg * 4;
#pragma unroll
  for (int c = 0; c < 8; ++c) {
    const size_t off = (size_t)b * CHW + (size_t)(d0 + c) * HWI + oy * WW + ox;
    *(float4*)(out + off) = make_float4(acc[c][0], acc[c][1], acc[c][2], acc[c][3]);
  }
}

// ---------------------------------------------------------------------------
extern "C" void kernel_launch(void* const* d_in, const int* in_sizes, int n_in,
                              void* d_out, int out_size, void* d_ws, size_t ws_size,
                              hipStream_t stream)
{
  const float* x  = (const float*)d_in[0];
  const float* W1 = (const float*)d_in[1];
  const float* W2 = (const float*)d_in[2];
  const float* W3 = (const float*)d_in[3];

  float* ws    = (float*)d_ws;
  float* Y1    = ws;                 // IMG floats
  float* Y2    = ws + IMG;           // IMG floats
  float* attnT = ws + 2 * (size_t)IMG;        // ATT floats
  float* attnW = attnT + ATT;        // ATT floats
  float* Y3    = Y1;                 // Y1 dead after attn_gemm -> reuse slot
  // total ws use: 2*IMG + 2*ATT floats = ~124 MB

  const dim3 cgrid(12, 9, BB);       // co-groups x spatial tiles x batch

  conv_dual  <<<cgrid, 256, 0, stream>>>(x, W1, W2, Y1, Y2);
  attn_gemm  <<<BB * 9, 1024, 0, stream>>>(Y1, Y2, attnT);
  softmax_k  <<<BB * CH, 256, 0, stream>>>(attnT, attnW);
  conv_single<<<cgrid, 256, 0, stream>>>(x, W3, Y3);
  conv_attn  <<<cgrid, 256, 0, stream>>>(Y3, attnW, (float*)d_out);
}

// Round 2
// 544.450 us; speedup vs baseline: 3.6690x; 3.6690x over previous
//
#include <hip/hip_runtime.h>
#include <math.h>

// Problem constants
constexpr int BB  = 16;
constexpr int CH  = 96;            // CIN == COUT == 96
constexpr int HH  = 96;
constexpr int WW  = 96;
constexpr int HWI = HH * WW;       // 9216
constexpr int CHW = CH * HWI;      // 884736
constexpr int IMG = BB * CHW;      // floats per [B,C,H,W] tensor
constexpr int ATT = BB * CH * CH * 9;  // 1327104 floats
constexpr int WPK = 27 * 6 * 64 * 8;   // 82944 bf16 elems per packed weight matrix

typedef short short8 __attribute__((ext_vector_type(8)));
typedef float floatx4 __attribute__((ext_vector_type(4)));

__device__ __forceinline__ ushort f2bf(float f) {
  union { float f; unsigned u; } v; v.f = f;
  unsigned r = (v.u + 0x7fffu + ((v.u >> 16) & 1u)) >> 16;  // RNE
  return (ushort)r;
}

// ---------------------------------------------------------------------------
// Weight prepack: fp32 source with element (m, ci, o) at src[m*864 + ci*9 + o]
// (o = kh*3+kw) -> bf16 packed in MFMA A-fragment lane order for GEMM-K
// ordering k = o*96 + ci, chunks of 32:
//   packed[((kc*6 + mt)*64 + lane)*8 + j] = W[m = mt*16 + (lane&15)]
//                                            [k = kc*32 + (lane>>4)*8 + j]
// grid.y = matrix index g (stride 82944 in both src and dst).
// ---------------------------------------------------------------------------
__global__ __launch_bounds__(256) void prepack(
    const float* __restrict__ src, ushort* __restrict__ dst)
{
  const int g = blockIdx.y;
  const int p = blockIdx.x * 256 + threadIdx.x;   // 0..82943
  const float* s = src + (size_t)g * WPK;
  ushort* d = dst + (size_t)g * WPK;
  const int j    = p & 7;
  const int lane = (p >> 3) & 63;
  const int rest = p >> 9;                        // 0..161
  const int mt = rest % 6;
  const int kc = rest / 6;
  const int m  = mt * 16 + (lane & 15);
  const int k  = kc * 32 + (lane >> 4) * 8 + j;
  const int ci = k % 96;
  const int o  = k / 96;
  d[p] = f2bf(s[m * 864 + ci * 9 + o]);
}

// ---------------------------------------------------------------------------
// Implicit-GEMM 3x3 conv via MFMA 16x16x32 bf16.
//   Y[b][co][y][x] = sum_{ci,kh,kw} W[co][ci,kh,kw] * X[b][ci][y+kh-1][x+kw-1]
// Block: 256 thr (4 waves), one (b, 12x16 spatial tile). M=96 (all co),
// N=192 pixels (12 rows x 16 cols), K=864 in 27 chunks of 32.
// X tile (14x18 halo x 96ci) staged ONCE in LDS, pixel-major [pix][ci] bf16
// (stride 104 for bank spread) -> B frags are single ds_read_b128.
// A frags: coalesced dwordx4 from packed weights (L1/L2-hot, 6KB per chunk).
// K-loop is completely sync-free.
// wbstride: 0 for shared weights, WPK for per-batch (attention) weights.
// ---------------------------------------------------------------------------
__global__ __launch_bounds__(256, 2) void conv_mfma(
    const float* __restrict__ X, const ushort* __restrict__ Wpk,
    float* __restrict__ Y, int wbstride)
{
  const int b    = blockIdx.y;
  const int tile = blockIdx.x;
  const int ty0  = (tile / 6) * 12;
  const int tx0  = (tile % 6) * 16;
  const int tid  = threadIdx.x;
  const int lane = tid & 63;
  const int w    = tid >> 6;       // wave 0..3 -> output rows 3w..3w+2
  const int nc   = lane & 15;      // pixel col within tile
  const int q    = lane >> 4;      // k-quad

  __shared__ ushort Xs[252 * 104]; // 14x18 pixels x 96 ci (pad to 104)

  // ---- stage X tile as bf16, pixel-major ----
  if (tid < 252) {
    const int ly = tid / 18, lx = tid % 18;
    const int gy = ty0 - 1 + ly, gx = tx0 - 1 + lx;
    const bool inb = ((unsigned)gy < 96u) & ((unsigned)gx < 96u);
    const float* src = X + (size_t)b * CHW + gy * WW + gx;
    ushort* dst = &Xs[tid * 104];
#pragma unroll 4
    for (int cg = 0; cg < 24; ++cg) {
      float f0 = 0.f, f1 = 0.f, f2 = 0.f, f3 = 0.f;
      if (inb) {
        const float* s = src + (size_t)(cg * 4) * HWI;
        f0 = s[0]; f1 = s[HWI]; f2 = s[2 * HWI]; f3 = s[3 * HWI];
      }
      ushort4 u;
      u.x = f2bf(f0); u.y = f2bf(f1); u.z = f2bf(f2); u.w = f2bf(f3);
      *(ushort4*)(dst + cg * 4) = u;   // ds_write_b64
    }
  }
  __syncthreads();

  const ushort* wp = Wpk + (size_t)b * wbstride;

  floatx4 acc[6][3];
#pragma unroll
  for (int mt = 0; mt < 6; ++mt)
#pragma unroll
    for (int t = 0; t < 3; ++t)
#pragma unroll
      for (int r = 0; r < 4; ++r) acc[mt][t][r] = 0.f;

  for (int o = 0; o < 9; ++o) {          // spatial offset (kh*3+kw)
    const int dy = o / 3, dx = o % 3;
    const int pc = nc + dx;
#pragma unroll
    for (int cc = 0; cc < 3; ++cc) {     // 3 ci-chunks of 32 per offset
      const int kc  = o * 3 + cc;
      const int cib = cc * 32 + q * 8;

      short8 bfr[3];
#pragma unroll
      for (int t = 0; t < 3; ++t) {
        const int pix = (3 * w + t + dy) * 18 + pc;
        bfr[t] = *(const short8*)(&Xs[pix * 104 + cib]);  // ds_read_b128
      }

      const ushort* ap = wp + (size_t)(kc * 6) * 512 + lane * 8;
#pragma unroll
      for (int mt = 0; mt < 6; ++mt) {
        const short8 af = *(const short8*)(ap + mt * 512); // global dwordx4
#pragma unroll
        for (int t = 0; t < 3; ++t)
          acc[mt][t] = __builtin_amdgcn_mfma_f32_16x16x32_bf16(
              af, bfr[t], acc[mt][t], 0, 0, 0);
      }
    }
  }

  // ---- epilogue: C/D layout col=lane&15 (pixel), row=(lane>>4)*4+r (co) ----
  float* yb = Y + (size_t)b * CHW;
#pragma unroll
  for (int mt = 0; mt < 6; ++mt)
#pragma unroll
    for (int t = 0; t < 3; ++t) {
      const int yy = ty0 + 3 * w + t;
      const int xx = tx0 + nc;
#pragma unroll
      for (int r = 0; r < 4; ++r) {
        const int co = mt * 16 + q * 4 + r;
        yb[(size_t)co * HWI + yy * WW + xx] = acc[mt][t][r];
      }
    }
}

// ---------------------------------------------------------------------------
// Attention Gram GEMM (unchanged from passing round-1 version).
// attn[b,k,c,d] = sum over the 32x32 pixel subset {h%3==kh, w%3==kw} of
//                 Y1[b,c,p] * Y2[b,d,p].  Output in transposed layout
//                 attnT[b][d][c][k] for contiguous softmax rows.
// ---------------------------------------------------------------------------
__global__ __launch_bounds__(1024) void attn_gemm(
    const float* __restrict__ Y1, const float* __restrict__ Y2,
    float* __restrict__ attnT)
{
  const int b  = blockIdx.x / 9;
  const int k  = blockIdx.x % 9;
  const int kh = k / 3, kw = k % 3;
  const int tid = threadIdx.x;
  const int td = tid & 31;
  const int tc = tid >> 5;

  __shared__ float as[96][33];
  __shared__ float bs[96][33];

  float acc[3][3];
#pragma unroll
  for (int r = 0; r < 3; ++r)
#pragma unroll
    for (int s = 0; s < 3; ++s) acc[r][s] = 0.f;

  const float* y1b = Y1 + (size_t)b * CHW;
  const float* y2b = Y2 + (size_t)b * CHW;

  for (int i = 0; i < 32; ++i) {
    __syncthreads();
    const int row = (3 * i + kh) * WW + kw;
    for (int t = tid; t < 96 * 32; t += 1024) {
      const int c = t >> 5;
      const int j = t & 31;
      as[c][j] = y1b[c * HWI + row + 3 * j];
      bs[c][j] = y2b[c * HWI + row + 3 * j];
    }
    __syncthreads();

#pragma unroll 4
    for (int j = 0; j < 32; ++j) {
      const float a0 = as[tc][j], a1 = as[tc + 32][j], a2 = as[tc + 64][j];
      const float b0 = bs[td][j], b1 = bs[td + 32][j], b2 = bs[td + 64][j];
      acc[0][0] = fmaf(a0, b0, acc[0][0]);
      acc[0][1] = fmaf(a0, b1, acc[0][1]);
      acc[0][2] = fmaf(a0, b2, acc[0][2]);
      acc[1][0] = fmaf(a1, b0, acc[1][0]);
      acc[1][1] = fmaf(a1, b1, acc[1][1]);
      acc[1][2] = fmaf(a1, b2, acc[1][2]);
      acc[2][0] = fmaf(a2, b0, acc[2][0]);
      acc[2][1] = fmaf(a2, b1, acc[2][1]);
      acc[2][2] = fmaf(a2, b2, acc[2][2]);
    }
  }

#pragma unroll
  for (int r = 0; r < 3; ++r)
#pragma unroll
    for (int s = 0; s < 3; ++s) {
      const int c = tc + 32 * r;
      const int d = td + 32 * s;
      attnT[((size_t)(b * CH + d) * CH + c) * 9 + k] = acc[r][s];
    }
}

// ---------------------------------------------------------------------------
// Softmax over m = c*9+k (864 values) per (b,d) row (unchanged).
// ---------------------------------------------------------------------------
__global__ __launch_bounds__(256) void softmax_k(
    const float* __restrict__ attnT, float* __restrict__ attnW)
{
  const int bd = blockIdx.x;
  const float* src = attnT + (size_t)bd * 864;
  float* dst = attnW + (size_t)bd * 864;
  const float rs = 0.0340216824f;          // 1/sqrt(864)
  const int tid = threadIdx.x;

  float v0 = src[tid];
  float v1 = src[tid + 256];
  float v2 = src[tid + 512];
  float v3 = (tid < 96) ? src[tid + 768] : -3.0e38f;

  float mx = fmaxf(fmaxf(v0, v1), fmaxf(v2, v3));

  __shared__ float red[256];
  red[tid] = mx;
  __syncthreads();
#pragma unroll
  for (int s = 128; s > 0; s >>= 1) {
    if (tid < s) red[tid] = fmaxf(red[tid], red[tid + s]);
    __syncthreads();
  }
  mx = red[0];
  __syncthreads();

  const float e0 = expf((v0 - mx) * rs);
  const float e1 = expf((v1 - mx) * rs);
  const float e2 = expf((v2 - mx) * rs);
  const float e3 = (tid < 96) ? expf((v3 - mx) * rs) : 0.f;

  red[tid] = e0 + e1 + e2 + e3;
  __syncthreads();
#pragma unroll
  for (int s = 128; s > 0; s >>= 1) {
    if (tid < s) red[tid] += red[tid + s];
    __syncthreads();
  }
  const float inv = 1.f / red[0];

  dst[tid]       = e0 * inv;
  dst[tid + 256] = e1 * inv;
  dst[tid + 512] = e2 * inv;
  if (tid < 96) dst[tid + 768] = e3 * inv;
}

// ---------------------------------------------------------------------------
extern "C" void kernel_launch(void* const* d_in, const int* in_sizes, int n_in,
                              void* d_out, int out_size, void* d_ws, size_t ws_size,
                              hipStream_t stream)
{
  const float* x  = (const float*)d_in[0];
  const float* W1 = (const float*)d_in[1];
  const float* W2 = (const float*)d_in[2];
  const float* W3 = (const float*)d_in[3];

  float* ws    = (float*)d_ws;
  float* Y1    = ws;                        // IMG floats
  float* Y2    = ws + (size_t)IMG;          // IMG floats
  float* attnT = ws + 2 * (size_t)IMG;      // ATT floats
  float* attnW = attnT + ATT;               // ATT floats
  ushort* pk   = (ushort*)(ws + 2 * (size_t)IMG + 2 * (size_t)ATT);
  ushort* pkW1 = pk;
  ushort* pkW2 = pk + WPK;
  ushort* pkW3 = pk + 2 * (size_t)WPK;
  ushort* pkAW = pk + 3 * (size_t)WPK;      // 16 batch matrices
  float* Y3    = Y1;                        // Y1 dead after attn_gemm
  // ws use: 2*IMG + 2*ATT floats + 19*WPK ushorts  ~= 121 MB

  const dim3 cgrid(48, BB);                 // 8x6 spatial tiles x batch

  prepack  <<<dim3(324, 1),  256, 0, stream>>>(W1, pkW1);
  prepack  <<<dim3(324, 1),  256, 0, stream>>>(W2, pkW2);
  prepack  <<<dim3(324, 1),  256, 0, stream>>>(W3, pkW3);

  conv_mfma<<<cgrid, 256, 0, stream>>>(x, pkW1, Y1, 0);
  conv_mfma<<<cgrid, 256, 0, stream>>>(x, pkW2, Y2, 0);

  attn_gemm<<<BB * 9, 1024, 0, stream>>>(Y1, Y2, attnT);
  softmax_k<<<BB * CH, 256, 0, stream>>>(attnT, attnW);

  prepack  <<<dim3(324, BB), 256, 0, stream>>>(attnW, pkAW);

  conv_mfma<<<cgrid, 256, 0, stream>>>(x, pkW3, Y3, 0);
  conv_mfma<<<cgrid, 256, 0, stream>>>(Y3, pkAW, (float*)d_out, WPK);
}

// Round 3
// 457.644 us; speedup vs baseline: 4.3649x; 1.1897x over previous
//
#include <hip/hip_runtime.h>
#include <math.h>

// Problem constants
constexpr int BB  = 16;
constexpr int CH  = 96;            // CIN == COUT == 96
constexpr int HH  = 96;
constexpr int WW  = 96;
constexpr int HWI = HH * WW;       // 9216
constexpr int CHW = CH * HWI;      // 884736
constexpr int IMG = BB * CHW;      // floats per [B,C,H,W] tensor
constexpr int ATT = BB * CH * CH * 9;  // 1327104 floats
constexpr int WPK = 27 * 6 * 64 * 8;   // 82944 bf16 elems per packed weight matrix

typedef short short8 __attribute__((ext_vector_type(8)));
typedef float floatx4 __attribute__((ext_vector_type(4)));

__device__ __forceinline__ ushort f2bf(float f) {
  union { float f; unsigned u; } v; v.f = f;
  unsigned r = (v.u + 0x7fffu + ((v.u >> 16) & 1u)) >> 16;  // RNE
  return (ushort)r;
}
__device__ __forceinline__ float bf2f(ushort h) {
  union { float f; unsigned u; } v; v.u = ((unsigned)h) << 16;
  return v.f;
}

// ---------------------------------------------------------------------------
// Weight prepack (unchanged): fp32 (m, ci, o) at src[m*864 + ci*9 + o] ->
// bf16 in MFMA A-frag lane order for K ordering k = o*96 + ci, chunks of 32.
// ---------------------------------------------------------------------------
__global__ __launch_bounds__(256) void prepack(
    const float* __restrict__ src, ushort* __restrict__ dst)
{
  const int g = blockIdx.y;
  const int p = blockIdx.x * 256 + threadIdx.x;   // 0..82943
  const float* s = src + (size_t)g * WPK;
  ushort* d = dst + (size_t)g * WPK;
  const int j    = p & 7;
  const int lane = (p >> 3) & 63;
  const int rest = p >> 9;                        // 0..161
  const int mt = rest % 6;
  const int kc = rest / 6;
  const int m  = mt * 16 + (lane & 15);
  const int k  = kc * 32 + (lane >> 4) * 8 + j;
  const int ci = k % 96;
  const int o  = k / 96;
  d[p] = f2bf(s[m * 864 + ci * 9 + o]);
}

// ---------------------------------------------------------------------------
// Implicit-GEMM 3x3 conv via MFMA 16x16x32 bf16 (unchanged structure).
// ---------------------------------------------------------------------------
__global__ __launch_bounds__(256, 2) void conv_mfma(
    const float* __restrict__ X, const ushort* __restrict__ Wpk,
    float* __restrict__ Y, int wbstride)
{
  const int b    = blockIdx.y;
  const int tile = blockIdx.x;
  const int ty0  = (tile / 6) * 12;
  const int tx0  = (tile % 6) * 16;
  const int tid  = threadIdx.x;
  const int lane = tid & 63;
  const int w    = tid >> 6;
  const int nc   = lane & 15;
  const int q    = lane >> 4;

  __shared__ ushort Xs[252 * 104];

  if (tid < 252) {
    const int ly = tid / 18, lx = tid % 18;
    const int gy = ty0 - 1 + ly, gx = tx0 - 1 + lx;
    const bool inb = ((unsigned)gy < 96u) & ((unsigned)gx < 96u);
    const float* src = X + (size_t)b * CHW + gy * WW + gx;
    ushort* dst = &Xs[tid * 104];
#pragma unroll 4
    for (int cg = 0; cg < 24; ++cg) {
      float f0 = 0.f, f1 = 0.f, f2 = 0.f, f3 = 0.f;
      if (inb) {
        const float* s = src + (size_t)(cg * 4) * HWI;
        f0 = s[0]; f1 = s[HWI]; f2 = s[2 * HWI]; f3 = s[3 * HWI];
      }
      ushort4 u;
      u.x = f2bf(f0); u.y = f2bf(f1); u.z = f2bf(f2); u.w = f2bf(f3);
      *(ushort4*)(dst + cg * 4) = u;
    }
  }
  __syncthreads();

  const ushort* wp = Wpk + (size_t)b * wbstride;

  floatx4 acc[6][3];
#pragma unroll
  for (int mt = 0; mt < 6; ++mt)
#pragma unroll
    for (int t = 0; t < 3; ++t)
#pragma unroll
      for (int r = 0; r < 4; ++r) acc[mt][t][r] = 0.f;

  for (int o = 0; o < 9; ++o) {
    const int dy = o / 3, dx = o % 3;
    const int pc = nc + dx;
#pragma unroll
    for (int cc = 0; cc < 3; ++cc) {
      const int kc  = o * 3 + cc;
      const int cib = cc * 32 + q * 8;

      short8 bfr[3];
#pragma unroll
      for (int t = 0; t < 3; ++t) {
        const int pix = (3 * w + t + dy) * 18 + pc;
        bfr[t] = *(const short8*)(&Xs[pix * 104 + cib]);
      }

      const ushort* ap = wp + (size_t)(kc * 6) * 512 + lane * 8;
#pragma unroll
      for (int mt = 0; mt < 6; ++mt) {
        const short8 af = *(const short8*)(ap + mt * 512);
#pragma unroll
        for (int t = 0; t < 3; ++t)
          acc[mt][t] = __builtin_amdgcn_mfma_f32_16x16x32_bf16(
              af, bfr[t], acc[mt][t], 0, 0, 0);
      }
    }
  }

  float* yb = Y + (size_t)b * CHW;
#pragma unroll
  for (int mt = 0; mt < 6; ++mt)
#pragma unroll
    for (int t = 0; t < 3; ++t) {
      const int yy = ty0 + 3 * w + t;
      const int xx = tx0 + nc;
#pragma unroll
      for (int r = 0; r < 4; ++r) {
        const int co = mt * 16 + q * 4 + r;
        yb[(size_t)co * HWI + yy * WW + xx] = acc[mt][t][r];
      }
    }
}

// ---------------------------------------------------------------------------
// Dual-output conv: Y1=conv(x,W1), Y2=conv(x,W2) sharing one LDS staging.
// 36 MFMA per 3 ds_read_b128 per chunk (2x arithmetic intensity of single).
// acc = 144 VGPR; fits under the 256-VGPR cap of (256,2).
// ---------------------------------------------------------------------------
__global__ __launch_bounds__(256, 2) void conv_dual_mfma(
    const float* __restrict__ X,
    const ushort* __restrict__ WpkA, const ushort* __restrict__ WpkB,
    float* __restrict__ YA, float* __restrict__ YB)
{
  const int b    = blockIdx.y;
  const int tile = blockIdx.x;
  const int ty0  = (tile / 6) * 12;
  const int tx0  = (tile % 6) * 16;
  const int tid  = threadIdx.x;
  const int lane = tid & 63;
  const int w    = tid >> 6;
  const int nc   = lane & 15;
  const int q    = lane >> 4;

  __shared__ ushort Xs[252 * 104];

  if (tid < 252) {
    const int ly = tid / 18, lx = tid % 18;
    const int gy = ty0 - 1 + ly, gx = tx0 - 1 + lx;
    const bool inb = ((unsigned)gy < 96u) & ((unsigned)gx < 96u);
    const float* src = X + (size_t)b * CHW + gy * WW + gx;
    ushort* dst = &Xs[tid * 104];
#pragma unroll 4
    for (int cg = 0; cg < 24; ++cg) {
      float f0 = 0.f, f1 = 0.f, f2 = 0.f, f3 = 0.f;
      if (inb) {
        const float* s = src + (size_t)(cg * 4) * HWI;
        f0 = s[0]; f1 = s[HWI]; f2 = s[2 * HWI]; f3 = s[3 * HWI];
      }
      ushort4 u;
      u.x = f2bf(f0); u.y = f2bf(f1); u.z = f2bf(f2); u.w = f2bf(f3);
      *(ushort4*)(dst + cg * 4) = u;
    }
  }
  __syncthreads();

  floatx4 accA[6][3], accB[6][3];
#pragma unroll
  for (int mt = 0; mt < 6; ++mt)
#pragma unroll
    for (int t = 0; t < 3; ++t)
#pragma unroll
      for (int r = 0; r < 4; ++r) { accA[mt][t][r] = 0.f; accB[mt][t][r] = 0.f; }

  for (int o = 0; o < 9; ++o) {
    const int dy = o / 3, dx = o % 3;
    const int pc = nc + dx;
#pragma unroll
    for (int cc = 0; cc < 3; ++cc) {
      const int kc  = o * 3 + cc;
      const int cib = cc * 32 + q * 8;

      short8 bfr[3];
#pragma unroll
      for (int t = 0; t < 3; ++t) {
        const int pix = (3 * w + t + dy) * 18 + pc;
        bfr[t] = *(const short8*)(&Xs[pix * 104 + cib]);
      }

      const size_t abase = (size_t)(kc * 6) * 512 + lane * 8;
      const ushort* apA = WpkA + abase;
      const ushort* apB = WpkB + abase;
#pragma unroll
      for (int mt = 0; mt < 6; ++mt) {
        const short8 afA = *(const short8*)(apA + mt * 512);
#pragma unroll
        for (int t = 0; t < 3; ++t)
          accA[mt][t] = __builtin_amdgcn_mfma_f32_16x16x32_bf16(
              afA, bfr[t], accA[mt][t], 0, 0, 0);
        const short8 afB = *(const short8*)(apB + mt * 512);
#pragma unroll
        for (int t = 0; t < 3; ++t)
          accB[mt][t] = __builtin_amdgcn_mfma_f32_16x16x32_bf16(
              afB, bfr[t], accB[mt][t], 0, 0, 0);
      }
    }
  }

  float* yA = YA + (size_t)b * CHW;
  float* yB = YB + (size_t)b * CHW;
#pragma unroll
  for (int mt = 0; mt < 6; ++mt)
#pragma unroll
    for (int t = 0; t < 3; ++t) {
      const int yy = ty0 + 3 * w + t;
      const int xx = tx0 + nc;
#pragma unroll
      for (int r = 0; r < 4; ++r) {
        const int co = mt * 16 + q * 4 + r;
        yA[(size_t)co * HWI + yy * WW + xx] = accA[mt][t][r];
        yB[(size_t)co * HWI + yy * WW + xx] = accB[mt][t][r];
      }
    }
}

// ---------------------------------------------------------------------------
// Attention Gram GEMM via MFMA, split-bf16 (hi+lo) 3-pass for ~fp32 accuracy.
// attn[b,k,c,d] = sum_{p in class-k 32x32 grid} Y1[b,c,p] * Y2[b,d,p].
// One block per (b,k): K=1024 stays in-block (no partials/atomics).
// 1024 thr = 16 waves; waves 0..8 tile C 96x96 as 3x3 groups of 2x2 MFMA
// tiles; all 16 waves stage. K streamed in 16 slabs of 64 class-pixels:
// 4 bf16 planes [96][72] = 55.3 KB LDS (safe static limit).
// Output written in transposed layout attnT[b][d][c][k].
// ---------------------------------------------------------------------------
__global__ __launch_bounds__(1024) void attn_mfma(
    const float* __restrict__ Y1, const float* __restrict__ Y2,
    float* __restrict__ attnT)
{
  const int b  = blockIdx.x / 9;
  const int k  = blockIdx.x % 9;
  const int kh = k / 3, kw = k % 3;
  const int tid  = threadIdx.x;
  const int lane = tid & 63;
  const int wv   = tid >> 6;          // 0..15

  __shared__ ushort Ah[96 * 72], Al[96 * 72], Bh[96 * 72], Bl[96 * 72];

  const float* y1b = Y1 + (size_t)b * CHW;
  const float* y2b = Y2 + (size_t)b * CHW;

  // compute-wave tiling (waves 0..8): 2x2 tiles of 16x16
  const int mg = wv / 3;              // c-tile group
  const int ng = wv % 3;              // d-tile group
  const int cn = lane & 15;
  const int q  = lane >> 4;

  floatx4 acc[2][2];
#pragma unroll
  for (int i = 0; i < 2; ++i)
#pragma unroll
    for (int j = 0; j < 2; ++j)
#pragma unroll
      for (int r = 0; r < 4; ++r) acc[i][j][r] = 0.f;

  const int sj = tid & 31;            // staging: class-col index
  const int sg = tid >> 5;            // 0..31
  const int scol = 3 * sj + kw;

  for (int s = 0; s < 16; ++s) {      // slab: class-rows 2s, 2s+1
    __syncthreads();
#pragma unroll
    for (int c8 = 0; c8 < 3; ++c8) {
      const int c = c8 * 32 + sg;
      const int cbase = c * 72;
#pragma unroll
      for (int ii = 0; ii < 2; ++ii) {
        const int row = 3 * (s * 2 + ii) + kh;
        const int p   = ii * 32 + sj;
        const size_t goff = (size_t)c * HWI + row * WW + scol;
        const float v1 = y1b[goff];
        const float v2 = y2b[goff];
        const ushort h1 = f2bf(v1);
        const ushort h2 = f2bf(v2);
        Ah[cbase + p] = h1;
        Al[cbase + p] = f2bf(v1 - bf2f(h1));
        Bh[cbase + p] = h2;
        Bl[cbase + p] = f2bf(v2 - bf2f(h2));
      }
    }
    __syncthreads();

    if (wv < 9) {
#pragma unroll
      for (int kc = 0; kc < 2; ++kc) {
        short8 ah[2], al[2], bh[2], bl[2];
#pragma unroll
        for (int t = 0; t < 2; ++t) {
          const int offA = ((mg * 2 + t) * 16 + cn) * 72 + kc * 32 + q * 8;
          ah[t] = *(const short8*)(&Ah[offA]);
          al[t] = *(const short8*)(&Al[offA]);
          const int offB = ((ng * 2 + t) * 16 + cn) * 72 + kc * 32 + q * 8;
          bh[t] = *(const short8*)(&Bh[offB]);
          bl[t] = *(const short8*)(&Bl[offB]);
        }
#pragma unroll
        for (int i = 0; i < 2; ++i)
#pragma unroll
          for (int j = 0; j < 2; ++j) {
            acc[i][j] = __builtin_amdgcn_mfma_f32_16x16x32_bf16(
                ah[i], bh[j], acc[i][j], 0, 0, 0);
            acc[i][j] = __builtin_amdgcn_mfma_f32_16x16x32_bf16(
                ah[i], bl[j], acc[i][j], 0, 0, 0);
            acc[i][j] = __builtin_amdgcn_mfma_f32_16x16x32_bf16(
                al[i], bh[j], acc[i][j], 0, 0, 0);
          }
      }
    }
  }

  if (wv < 9) {
#pragma unroll
    for (int i = 0; i < 2; ++i)
#pragma unroll
      for (int j = 0; j < 2; ++j)
#pragma unroll
        for (int r = 0; r < 4; ++r) {
          const int c = (mg * 2 + i) * 16 + q * 4 + r;
          const int d = (ng * 2 + j) * 16 + cn;
          attnT[((size_t)(b * CH + d) * CH + c) * 9 + k] = acc[i][j][r];
        }
  }
}

// ---------------------------------------------------------------------------
// Softmax over m = c*9+k (864 values) per (b,d) row (unchanged).
// ---------------------------------------------------------------------------
__global__ __launch_bounds__(256) void softmax_k(
    const float* __restrict__ attnT, float* __restrict__ attnW)
{
  const int bd = blockIdx.x;
  const float* src = attnT + (size_t)bd * 864;
  float* dst = attnW + (size_t)bd * 864;
  const float rs = 0.0340216824f;          // 1/sqrt(864)
  const int tid = threadIdx.x;

  float v0 = src[tid];
  float v1 = src[tid + 256];
  float v2 = src[tid + 512];
  float v3 = (tid < 96) ? src[tid + 768] : -3.0e38f;

  float mx = fmaxf(fmaxf(v0, v1), fmaxf(v2, v3));

  __shared__ float red[256];
  red[tid] = mx;
  __syncthreads();
#pragma unroll
  for (int s = 128; s > 0; s >>= 1) {
    if (tid < s) red[tid] = fmaxf(red[tid], red[tid + s]);
    __syncthreads();
  }
  mx = red[0];
  __syncthreads();

  const float e0 = expf((v0 - mx) * rs);
  const float e1 = expf((v1 - mx) * rs);
  const float e2 = expf((v2 - mx) * rs);
  const float e3 = (tid < 96) ? expf((v3 - mx) * rs) : 0.f;

  red[tid] = e0 + e1 + e2 + e3;
  __syncthreads();
#pragma unroll
  for (int s = 128; s > 0; s >>= 1) {
    if (tid < s) red[tid] += red[tid + s];
    __syncthreads();
  }
  const float inv = 1.f / red[0];

  dst[tid]       = e0 * inv;
  dst[tid + 256] = e1 * inv;
  dst[tid + 512] = e2 * inv;
  if (tid < 96) dst[tid + 768] = e3 * inv;
}

// ---------------------------------------------------------------------------
extern "C" void kernel_launch(void* const* d_in, const int* in_sizes, int n_in,
                              void* d_out, int out_size, void* d_ws, size_t ws_size,
                              hipStream_t stream)
{
  const float* x  = (const float*)d_in[0];
  const float* W1 = (const float*)d_in[1];
  const float* W2 = (const float*)d_in[2];
  const float* W3 = (const float*)d_in[3];

  float* ws    = (float*)d_ws;
  float* Y1    = ws;                        // IMG floats
  float* Y2    = ws + (size_t)IMG;          // IMG floats
  float* attnT = ws + 2 * (size_t)IMG;      // ATT floats
  float* attnW = attnT + ATT;               // ATT floats
  ushort* pk   = (ushort*)(ws + 2 * (size_t)IMG + 2 * (size_t)ATT);
  ushort* pkW1 = pk;
  ushort* pkW2 = pk + WPK;
  ushort* pkW3 = pk + 2 * (size_t)WPK;
  ushort* pkAW = pk + 3 * (size_t)WPK;      // 16 batch matrices
  float* Y3    = Y1;                        // Y1 dead after attn_mfma
  // ws use: 2*IMG + 2*ATT floats + 19*WPK ushorts ~= 124 MB

  const dim3 cgrid(48, BB);                 // 8x6 spatial tiles x batch

  prepack  <<<dim3(324, 1),  256, 0, stream>>>(W1, pkW1);
  prepack  <<<dim3(324, 1),  256, 0, stream>>>(W2, pkW2);
  prepack  <<<dim3(324, 1),  256, 0, stream>>>(W3, pkW3);

  conv_dual_mfma<<<cgrid, 256, 0, stream>>>(x, pkW1, pkW2, Y1, Y2);

  attn_mfma<<<BB * 9, 1024, 0, stream>>>(Y1, Y2, attnT);
  softmax_k<<<BB * CH, 256, 0, stream>>>(attnT, attnW);

  prepack  <<<dim3(324, BB), 256, 0, stream>>>(attnW, pkAW);

  conv_mfma<<<cgrid, 256, 0, stream>>>(x, pkW3, Y3, 0);
  conv_mfma<<<cgrid, 256, 0, stream>>>(Y3, pkAW, (float*)d_out, WPK);
}